// Round 3
// baseline (338.433 us; speedup 1.0000x reference)
//
#include <hip/hip_runtime.h>
#include <hip/hip_bf16.h>

#define DIM 512
#define NH 8
#define DH 64
#define HW 1024     // 32*32
#define NPIX 8192   // 8*32*32

typedef __attribute__((ext_vector_type(8))) short s16x8;
typedef __attribute__((ext_vector_type(4))) float f32x4;

union B8 { s16x8 v; __hip_bfloat16 h[8]; };

// ---- kernel A: wvt[c*8+n] = sum_d wv[n*64+d][c]   (transposed [c][n] layout)
__global__ __launch_bounds__(64) void k_wvsum(const float* __restrict__ wv,
                                              float* __restrict__ wvt) {
  const int n = blockIdx.x;     // head
  const int t = threadIdx.x;    // c-chunk: c = 8t .. 8t+8
  float acc[8] = {0.f,0.f,0.f,0.f,0.f,0.f,0.f,0.f};
  const float* base = wv + (size_t)n * DH * DIM + t * 8;
  for (int d = 0; d < DH; ++d) {
    const f32x4 a = *(const f32x4*)(base + (size_t)d * DIM);
    const f32x4 b = *(const f32x4*)(base + (size_t)d * DIM + 4);
#pragma unroll
    for (int j = 0; j < 4; ++j) { acc[j] += a[j]; acc[4 + j] += b[j]; }
  }
#pragma unroll
  for (int j = 0; j < 8; ++j) wvt[(t * 8 + j) * NH + n] = acc[j];
}

// ---- kernel B: vs[(b*8+n)*1024 + xy] = sum_c x[p][c] * wvt[c][n],  p = b*1024+xy
__global__ __launch_bounds__(256) void k_vsum(const float* __restrict__ x,
                                              const float* __restrict__ wvt,
                                              float* __restrict__ vs) {
  const int t = threadIdx.x, wave = t >> 6, lane = t & 63;
  const int p = blockIdx.x * 4 + wave;           // one wave per pixel
  const float* xp = x + (size_t)p * DIM + lane * 8;
  const f32x4 x0 = *(const f32x4*)(xp);
  const f32x4 x1 = *(const f32x4*)(xp + 4);
  float xf[8];
#pragma unroll
  for (int j = 0; j < 4; ++j) { xf[j] = x0[j]; xf[4 + j] = x1[j]; }
  float acc[8] = {0.f,0.f,0.f,0.f,0.f,0.f,0.f,0.f};
  const float* wp = wvt + lane * 64;             // 64 contiguous floats: c=8l..8l+8, n=0..8
#pragma unroll
  for (int cc = 0; cc < 8; ++cc) {
    const f32x4 a = *(const f32x4*)(wp + cc * 8);
    const f32x4 b = *(const f32x4*)(wp + cc * 8 + 4);
#pragma unroll
    for (int j = 0; j < 4; ++j) { acc[j] += xf[cc] * a[j]; acc[4 + j] += xf[cc] * b[j]; }
  }
#pragma unroll
  for (int off = 32; off >= 1; off >>= 1) {
#pragma unroll
    for (int j = 0; j < 8; ++j) acc[j] += __shfl_xor(acc[j], off, 64);
  }
  if (lane == 0) {
    const int b_ = p >> 10, xy = p & 1023;
#pragma unroll
    for (int j = 0; j < 8; ++j) vs[(size_t)(b_ * NH + j) * HW + xy] = acc[j];
  }
}

// ---- kernel C: q/k projections via MFMA (fp32 inputs staged as bf16),
// per-head dot, scale, softmax over w.
// grid (128 pixel-groups of 64, 8 heads), block 256 (4 waves; wave = 16 pixels).
#define LDK 72   // padded leading dim (bf16 elems): 144B rows -> 2-way (free) bank aliasing
__global__ __launch_bounds__(256) void k_qk(const float* __restrict__ x,
                                            const float* __restrict__ wq,
                                            const float* __restrict__ wk,
                                            float* __restrict__ sw) {
  __shared__ __hip_bfloat16 xs[64 * LDK];
  __shared__ __hip_bfloat16 wqs[64 * LDK];
  __shared__ __hip_bfloat16 wks[64 * LDK];
  __shared__ float wraw[64];

  const int t = threadIdx.x;
  const int wave = t >> 6, lane = t & 63;
  const int lrow = lane & 15, quad = lane >> 4;
  const int pix0 = blockIdx.x * 64;
  const int head = blockIdx.y;

  const float* xg = x + (size_t)pix0 * DIM;
  const float* qg = wq + (size_t)head * DH * DIM;
  const float* kg = wk + (size_t)head * DH * DIM;

  f32x4 accq[4], acck[4];
#pragma unroll
  for (int s = 0; s < 4; ++s) { accq[s] = (f32x4)0.f; acck[s] = (f32x4)0.f; }

  for (int k0 = 0; k0 < DIM; k0 += 64) {
    __syncthreads();   // previous-iter readers done before restaging
#pragma unroll
    for (int i = 0; i < 2; ++i) {
      const int j = t + i * 256;          // 512 chunks of 8 elems per tile
      const int row = j >> 3, col = j & 7;
      const size_t goff = (size_t)row * DIM + k0 + col * 8;
      const int loff = row * LDK + col * 8;
      B8 ux, uq, uk;
      {
        const f32x4 a = *(const f32x4*)(xg + goff);
        const f32x4 b = *(const f32x4*)(xg + goff + 4);
#pragma unroll
        for (int m = 0; m < 4; ++m) { ux.h[m] = __float2bfloat16(a[m]); ux.h[4 + m] = __float2bfloat16(b[m]); }
      }
      {
        const f32x4 a = *(const f32x4*)(qg + goff);
        const f32x4 b = *(const f32x4*)(qg + goff + 4);
#pragma unroll
        for (int m = 0; m < 4; ++m) { uq.h[m] = __float2bfloat16(a[m]); uq.h[4 + m] = __float2bfloat16(b[m]); }
      }
      {
        const f32x4 a = *(const f32x4*)(kg + goff);
        const f32x4 b = *(const f32x4*)(kg + goff + 4);
#pragma unroll
        for (int m = 0; m < 4; ++m) { uk.h[m] = __float2bfloat16(a[m]); uk.h[4 + m] = __float2bfloat16(b[m]); }
      }
      *(s16x8*)(xs + loff)  = ux.v;
      *(s16x8*)(wqs + loff) = uq.v;
      *(s16x8*)(wks + loff) = uk.v;
    }
    __syncthreads();
#pragma unroll
    for (int kk = 0; kk < 64; kk += 32) {
      const s16x8 a = *(const s16x8*)(xs + (wave * 16 + lrow) * LDK + kk + quad * 8);
#pragma unroll
      for (int s = 0; s < 4; ++s) {
        const s16x8 bq = *(const s16x8*)(wqs + (s * 16 + lrow) * LDK + kk + quad * 8);
        accq[s] = __builtin_amdgcn_mfma_f32_16x16x32_bf16(a, bq, accq[s], 0, 0, 0);
        const s16x8 bk = *(const s16x8*)(wks + (s * 16 + lrow) * LDK + kk + quad * 8);
        acck[s] = __builtin_amdgcn_mfma_f32_16x16x32_bf16(a, bk, acck[s], 0, 0, 0);
      }
    }
  }

  // epilogue: per-row dot over the 64 head-channels = sum over 4 subtiles + 16 lanes
#pragma unroll
  for (int r = 0; r < 4; ++r) {
    float pr = accq[0][r] * acck[0][r] + accq[1][r] * acck[1][r]
             + accq[2][r] * acck[2][r] + accq[3][r] * acck[3][r];
#pragma unroll
    for (int off = 1; off <= 8; off <<= 1) pr += __shfl_xor(pr, off, 64);
    if (lrow == 0) wraw[wave * 16 + quad * 4 + r] = pr * 0.125f;  // scale = d^-0.5 = 1/8
  }
  __syncthreads();

  // softmax over each 32-pixel w-group (block = exactly 2 groups), wave 0 only
  if (t < 64) {
    const float v = wraw[t];
    float m = v;
#pragma unroll
    for (int off = 1; off <= 16; off <<= 1) m = fmaxf(m, __shfl_xor(m, off, 64));
    const float e = __expf(v - m);
    float se = e;
#pragma unroll
    for (int off = 1; off <= 16; off <<= 1) se += __shfl_xor(se, off, 64);
    const int p = pix0 + t;
    const int b_ = p >> 10, hw = p & 1023;
    sw[(size_t)(b_ * NH + head) * HW + hw] = e / se;
  }
}

// ---- kernel D: out[bn][hw][xy] = sw[bn][hw] * vs[bn][xy], FP32 out, float4 stores.
// grid (32 row-groups of 32, 64 bn), block 256. Each thread owns one float4 xy-chunk.
__global__ __launch_bounds__(256) void k_out(const float* __restrict__ sw,
                                             const float* __restrict__ vs,
                                             float* __restrict__ out) {
  __shared__ float swl[32];
  const int bn = blockIdx.y;
  const int row0 = blockIdx.x * 32;
  const int t = threadIdx.x;
  if (t < 32) swl[t] = sw[(size_t)bn * HW + row0 + t];
  __syncthreads();
  const f32x4 va = *(const f32x4*)(vs + (size_t)bn * HW + t * 4);
  float* op = out + (size_t)bn * HW * HW + (size_t)row0 * HW + t * 4;
#pragma unroll 4
  for (int r = 0; r < 32; ++r) {
    const float w = swl[r];
    f32x4 o;
#pragma unroll
    for (int j = 0; j < 4; ++j) o[j] = w * va[j];
    *(f32x4*)(op + (size_t)r * HW) = o;
  }
}

extern "C" void kernel_launch(void* const* d_in, const int* in_sizes, int n_in,
                              void* d_out, int out_size, void* d_ws, size_t ws_size,
                              hipStream_t stream) {
  const float* x  = (const float*)d_in[0];
  const float* wq = (const float*)d_in[1];
  const float* wk = (const float*)d_in[2];
  const float* wv = (const float*)d_in[3];
  float* out = (float*)d_out;

  float* wvt = (float*)d_ws;        // 4096 floats   [c][n]
  float* vs  = wvt + 4096;          // 65536 floats  [bn][xy]
  float* sw  = vs + 65536;          // 65536 floats  [bn][hw]

  hipLaunchKernelGGL(k_wvsum, dim3(NH), dim3(64), 0, stream, wv, wvt);
  hipLaunchKernelGGL(k_vsum, dim3(NPIX / 4), dim3(256), 0, stream, x, wvt, vs);
  hipLaunchKernelGGL(k_qk, dim3(128, NH), dim3(256), 0, stream, x, wq, wk, sw);
  hipLaunchKernelGGL(k_out, dim3(32, 64), dim3(256), 0, stream, sw, vs, out);
}

// Round 4
// 330.195 us; speedup vs baseline: 1.0249x; 1.0249x over previous
//
#include <hip/hip_runtime.h>
#include <hip/hip_bf16.h>

#define DIM 512
#define NH 8
#define DH 64
#define HW 1024     // 32*32
#define NPIX 8192   // 8*32*32

typedef __attribute__((ext_vector_type(8))) short s16x8;
typedef __attribute__((ext_vector_type(4))) float f32x4;

union B8 { s16x8 v; __hip_bfloat16 h[8]; };

// ---- kernel A: wvt[c*8+n] = sum_d wv[n*64+d][c]   (transposed [c][n] layout)
// grid 64 = (head n = blk>>3) x (c-group of 64 = blk&7); one c per thread.
// Wave reads 64 consecutive c per d -> fully coalesced 256B segments; 64 waves
// of MLP instead of the old 8 (the old 8-wave version risked latency-binding).
__global__ __launch_bounds__(64) void k_wvsum(const float* __restrict__ wv,
                                              float* __restrict__ wvt) {
  const int n = blockIdx.x >> 3;
  const int c = (blockIdx.x & 7) * 64 + threadIdx.x;
  const float* base = wv + (size_t)n * DH * DIM + c;
  float acc = 0.f;
#pragma unroll 8
  for (int d = 0; d < DH; ++d) acc += base[(size_t)d * DIM];
  wvt[c * NH + n] = acc;
}

// ---- kernel B: vs[(b*8+n)*1024 + xy] = sum_c x[p][c] * wvt[c][n],  p = b*1024+xy
__global__ __launch_bounds__(256) void k_vsum(const float* __restrict__ x,
                                              const float* __restrict__ wvt,
                                              float* __restrict__ vs) {
  const int t = threadIdx.x, wave = t >> 6, lane = t & 63;
  const int p = blockIdx.x * 4 + wave;           // one wave per pixel
  const float* xp = x + (size_t)p * DIM + lane * 8;
  const f32x4 x0 = *(const f32x4*)(xp);
  const f32x4 x1 = *(const f32x4*)(xp + 4);
  float xf[8];
#pragma unroll
  for (int j = 0; j < 4; ++j) { xf[j] = x0[j]; xf[4 + j] = x1[j]; }
  float acc[8] = {0.f,0.f,0.f,0.f,0.f,0.f,0.f,0.f};
  const float* wp = wvt + lane * 64;             // 64 contiguous floats: c=8l..8l+8, n=0..8
#pragma unroll
  for (int cc = 0; cc < 8; ++cc) {
    const f32x4 a = *(const f32x4*)(wp + cc * 8);
    const f32x4 b = *(const f32x4*)(wp + cc * 8 + 4);
#pragma unroll
    for (int j = 0; j < 4; ++j) { acc[j] += xf[cc] * a[j]; acc[4 + j] += xf[cc] * b[j]; }
  }
#pragma unroll
  for (int off = 32; off >= 1; off >>= 1) {
#pragma unroll
    for (int j = 0; j < 8; ++j) acc[j] += __shfl_xor(acc[j], off, 64);
  }
  if (lane == 0) {
    const int b_ = p >> 10, xy = p & 1023;
#pragma unroll
    for (int j = 0; j < 8; ++j) vs[(size_t)(b_ * NH + j) * HW + xy] = acc[j];
  }
}

// ---- kernel C: q/k projections via MFMA (fp32 inputs staged as bf16),
// per-head dot, scale, softmax over w.
// grid (128 pixel-groups of 64, 8 heads), block 256 (4 waves; wave = 16 pixels).
#define LDK 72   // padded leading dim (bf16 elems): 144B rows -> 2-way (free) bank aliasing
__global__ __launch_bounds__(256) void k_qk(const float* __restrict__ x,
                                            const float* __restrict__ wq,
                                            const float* __restrict__ wk,
                                            float* __restrict__ sw) {
  __shared__ __hip_bfloat16 xs[64 * LDK];
  __shared__ __hip_bfloat16 wqs[64 * LDK];
  __shared__ __hip_bfloat16 wks[64 * LDK];
  __shared__ float wraw[64];

  const int t = threadIdx.x;
  const int wave = t >> 6, lane = t & 63;
  const int lrow = lane & 15, quad = lane >> 4;
  const int pix0 = blockIdx.x * 64;
  const int head = blockIdx.y;

  const float* xg = x + (size_t)pix0 * DIM;
  const float* qg = wq + (size_t)head * DH * DIM;
  const float* kg = wk + (size_t)head * DH * DIM;

  f32x4 accq[4], acck[4];
#pragma unroll
  for (int s = 0; s < 4; ++s) { accq[s] = (f32x4)0.f; acck[s] = (f32x4)0.f; }

  for (int k0 = 0; k0 < DIM; k0 += 64) {
    __syncthreads();   // previous-iter readers done before restaging
#pragma unroll
    for (int i = 0; i < 2; ++i) {
      const int j = t + i * 256;          // 512 chunks of 8 elems per tile
      const int row = j >> 3, col = j & 7;
      const size_t goff = (size_t)row * DIM + k0 + col * 8;
      const int loff = row * LDK + col * 8;
      B8 ux, uq, uk;
      {
        const f32x4 a = *(const f32x4*)(xg + goff);
        const f32x4 b = *(const f32x4*)(xg + goff + 4);
#pragma unroll
        for (int m = 0; m < 4; ++m) { ux.h[m] = __float2bfloat16(a[m]); ux.h[4 + m] = __float2bfloat16(b[m]); }
      }
      {
        const f32x4 a = *(const f32x4*)(qg + goff);
        const f32x4 b = *(const f32x4*)(qg + goff + 4);
#pragma unroll
        for (int m = 0; m < 4; ++m) { uq.h[m] = __float2bfloat16(a[m]); uq.h[4 + m] = __float2bfloat16(b[m]); }
      }
      {
        const f32x4 a = *(const f32x4*)(kg + goff);
        const f32x4 b = *(const f32x4*)(kg + goff + 4);
#pragma unroll
        for (int m = 0; m < 4; ++m) { uk.h[m] = __float2bfloat16(a[m]); uk.h[4 + m] = __float2bfloat16(b[m]); }
      }
      *(s16x8*)(xs + loff)  = ux.v;
      *(s16x8*)(wqs + loff) = uq.v;
      *(s16x8*)(wks + loff) = uk.v;
    }
    __syncthreads();
#pragma unroll
    for (int kk = 0; kk < 64; kk += 32) {
      const s16x8 a = *(const s16x8*)(xs + (wave * 16 + lrow) * LDK + kk + quad * 8);
#pragma unroll
      for (int s = 0; s < 4; ++s) {
        const s16x8 bq = *(const s16x8*)(wqs + (s * 16 + lrow) * LDK + kk + quad * 8);
        accq[s] = __builtin_amdgcn_mfma_f32_16x16x32_bf16(a, bq, accq[s], 0, 0, 0);
        const s16x8 bk = *(const s16x8*)(wks + (s * 16 + lrow) * LDK + kk + quad * 8);
        acck[s] = __builtin_amdgcn_mfma_f32_16x16x32_bf16(a, bk, acck[s], 0, 0, 0);
      }
    }
  }

  // epilogue: per-row dot over the 64 head-channels = sum over 4 subtiles + 16 lanes
#pragma unroll
  for (int r = 0; r < 4; ++r) {
    float pr = accq[0][r] * acck[0][r] + accq[1][r] * acck[1][r]
             + accq[2][r] * acck[2][r] + accq[3][r] * acck[3][r];
#pragma unroll
    for (int off = 1; off <= 8; off <<= 1) pr += __shfl_xor(pr, off, 64);
    if (lrow == 0) wraw[wave * 16 + quad * 4 + r] = pr * 0.125f;  // scale = d^-0.5 = 1/8
  }
  __syncthreads();

  // softmax over each 32-pixel w-group (block = exactly 2 groups), wave 0 only
  if (t < 64) {
    const float v = wraw[t];
    float m = v;
#pragma unroll
    for (int off = 1; off <= 16; off <<= 1) m = fmaxf(m, __shfl_xor(m, off, 64));
    const float e = __expf(v - m);
    float se = e;
#pragma unroll
    for (int off = 1; off <= 16; off <<= 1) se += __shfl_xor(se, off, 64);
    const int p = pix0 + t;
    const int b_ = p >> 10, hw = p & 1023;
    sw[(size_t)(b_ * NH + head) * HW + hw] = e / se;
  }
}

// ---- kernel D: out[bn][hw][xy] = sw[bn][hw] * vs[bn][xy], FP32 out, nt float4 stores.
// grid (32 row-groups of 32, 64 bn), block 256. Each thread owns one float4 xy-chunk.
__global__ __launch_bounds__(256) void k_out(const float* __restrict__ sw,
                                             const float* __restrict__ vs,
                                             float* __restrict__ out) {
  __shared__ float swl[32];
  const int bn = blockIdx.y;
  const int row0 = blockIdx.x * 32;
  const int t = threadIdx.x;
  if (t < 32) swl[t] = sw[(size_t)bn * HW + row0 + t];
  __syncthreads();
  const f32x4 va = *(const f32x4*)(vs + (size_t)bn * HW + t * 4);
  float* op = out + (size_t)bn * HW * HW + (size_t)row0 * HW + t * 4;
#pragma unroll 4
  for (int r = 0; r < 32; ++r) {
    const float w = swl[r];
    f32x4 o;
#pragma unroll
    for (int j = 0; j < 4; ++j) o[j] = w * va[j];
    __builtin_nontemporal_store(o, (f32x4*)(op + (size_t)r * HW));
  }
}

extern "C" void kernel_launch(void* const* d_in, const int* in_sizes, int n_in,
                              void* d_out, int out_size, void* d_ws, size_t ws_size,
                              hipStream_t stream) {
  const float* x  = (const float*)d_in[0];
  const float* wq = (const float*)d_in[1];
  const float* wk = (const float*)d_in[2];
  const float* wv = (const float*)d_in[3];
  float* out = (float*)d_out;

  float* wvt = (float*)d_ws;        // 4096 floats   [c][n]
  float* vs  = wvt + 4096;          // 65536 floats  [bn][xy]
  float* sw  = vs + 65536;          // 65536 floats  [bn][hw]

  hipLaunchKernelGGL(k_wvsum, dim3(64), dim3(64), 0, stream, wv, wvt);
  hipLaunchKernelGGL(k_vsum, dim3(NPIX / 4), dim3(256), 0, stream, x, wvt, vs);
  hipLaunchKernelGGL(k_qk, dim3(128, NH), dim3(256), 0, stream, x, wq, wk, sw);
  hipLaunchKernelGGL(k_out, dim3(32, 64), dim3(256), 0, stream, sw, vs, out);
}